// Round 15
// baseline (1257.073 us; speedup 1.0000x reference)
//
#include <hip/hip_runtime.h>
#include <math.h>

#define BB 64
#define T_SUB 512
#define WW 256
#define DD 768
#define HH 20
#define CAP_DIM 10
#define IN_DIM 778
#define KPAD 800
#define G4 80     // 4*H
#define NOUT 160

#define NCONS 128    // consumer blocks (2 dir x 64 b), dispatched FIRST
#define NPRODB 2560  // producer blocks: 8 slots x 64 b x 5 sub (640 thr each)

typedef _Float16 f16x8 __attribute__((ext_vector_type(8)));
typedef float f32x4 __attribute__((ext_vector_type(4)));
typedef unsigned int uint2v __attribute__((ext_vector_type(2)));

// ws layout (bytes):
//   wpad : [160][800] f16   @ 0          (256,000 B)
//   seg  : int2[16384]      @ 256,000    (131,072 B)
//   cnts : int[512]         @ 387,072    (2,048 B)   -- zeroed each call
//   x    : [16384][800] f16 @ 389,120    (26,214,400 B)
#define WP_OFF   ((size_t)0)
#define SEG_OFF  ((size_t)256000)
#define CT_OFF   ((size_t)387072)
#define X_OFF    ((size_t)389120)

// ---------------- K0: pad weights (blocks 0..159) + segment search (160..223)
__global__ __launch_bounds__(256) void k_prep(
    const float* __restrict__ wf, const float* __restrict__ wb,
    const int* __restrict__ b2t,
    _Float16* __restrict__ wp, int2* __restrict__ seg)
{
    int blk = blockIdx.x;
    if (blk < NOUT) {
        int j = blk;
        const float* src = (j < G4) ? (wf + (size_t)j * IN_DIM)
                                    : (wb + (size_t)(j - G4) * IN_DIM);
        for (int k = threadIdx.x; k < KPAD; k += 256)
            wp[(size_t)j * KPAD + k] = (k < IN_DIM) ? (_Float16)src[k] : (_Float16)0.f;
    } else {
        int b = blk - NOUT, w = threadIdx.x;
        const int* row = b2t + (size_t)b * T_SUB;
        int lo = 0, hi = T_SUB;
        while (lo < hi) { int m = (lo + hi) >> 1; if (row[m] < w) lo = m + 1; else hi = m; }
        int lo2 = lo, hi2 = T_SUB;
        while (lo2 < hi2) { int m = (lo2 + hi2) >> 1; if (row[m] < w + 1) lo2 = m + 1; else hi2 = m; }
        seg[(size_t)b * WW + w] = make_int2(lo, lo2 - lo);
    }
}

// relaxed poll (no per-iteration L1 invalidate — R12 lesson), acquire once after
__device__ __forceinline__ void waitc(const int* cnts, int idx) {
    int it = 0;
    while (__hip_atomic_load(&cnts[idx], __ATOMIC_RELAXED,
                             __HIP_MEMORY_SCOPE_AGENT) < 5) {
        __builtin_amdgcn_s_sleep(4);
        if (++it > 3000000) break;   // ~0.3 s failsafe
    }
}

__device__ __forceinline__ float xchg32(float v) {
    unsigned int a = __float_as_uint(v);
    uint2v r = __builtin_amdgcn_permlane32_swap(a, a, false, false);
    return __uint_as_float(r[0] ^ r[1] ^ a);   // partner lane's value (lane ^ 32)
}

// ---------------- K1: overlapped mega-kernel, 640-thread blocks -------------
// blocks 0..127    : consumers — R11-proven fused gemm+LSTM (waves 0..4;
//                    waves 5..9 idle, barrier-only). Gemm waves flag-wait.
// blocks 128..2687 : producers — R11-proven k_mean, 1 item/thread.
//                    5 blocks per (b, word-group); slot-major order
//                    ORDER={0,1,6,7,2,3,4,5} so both dirs' chunk0 land early.
__global__ __launch_bounds__(640) void k_mega(
    const float* __restrict__ hiddens, const int2* __restrict__ seg,
    const int* __restrict__ cap_inds, const float* __restrict__ cap_table,
    const _Float16* __restrict__ wp,
    const float* __restrict__ bias_f, const float* __restrict__ bias_b,
    const float* __restrict__ whh_f, const float* __restrict__ whh_b,
    _Float16* __restrict__ x, int* __restrict__ cnts,
    float* __restrict__ out)
{
    __shared__ float gbuf[2][64 * G4];   // 40 KB (consumer ping-pong)
    int blk = blockIdx.x;
    int t = threadIdx.x;

    if (blk >= NCONS) {
        // ===================== producer =====================
        const int ORDER[8] = {0, 1, 6, 7, 2, 3, 4, 5};
        int p = blk - NCONS;
        int s = p / 320, q = p % 320;
        int b = q / 5, sub = q % 5;
        int g = ORDER[s];
        int i = sub * 640 + t;           // 0..3199 within group
        int row = i / 100, d8 = i % 100;
        int bw = b * WW + g * 32 + row;
        f16x8 r;
        if (d8 < 96) {
            int2 sg = seg[bw];
            int lo = sg.x, cnt = sg.y;
            const size_t LSTR = (size_t)BB * (T_SUB + 1) * DD;
            const float* base = hiddens + ((size_t)b * (T_SUB + 1) + lo + 1) * DD + d8 * 8;
            float a[8];
#pragma unroll
            for (int u = 0; u < 8; u++) a[u] = 0.f;
            if (cnt == 2) {
#pragma unroll
                for (int l = 0; l < 3; ++l) {
                    float4 v0 = *(const float4*)(base + l * LSTR);
                    float4 v1 = *(const float4*)(base + l * LSTR + 4);
                    float4 v2 = *(const float4*)(base + l * LSTR + DD);
                    float4 v3 = *(const float4*)(base + l * LSTR + DD + 4);
                    a[0] += v0.x + v2.x; a[1] += v0.y + v2.y;
                    a[2] += v0.z + v2.z; a[3] += v0.w + v2.w;
                    a[4] += v1.x + v3.x; a[5] += v1.y + v3.y;
                    a[6] += v1.z + v3.z; a[7] += v1.w + v3.w;
                }
            } else {
                for (int l = 0; l < 3; ++l)
                    for (int ti = 0; ti < cnt; ++ti) {
                        const float* pp = base + l * LSTR + (size_t)ti * DD;
                        float4 v0 = *(const float4*)(pp);
                        float4 v1 = *(const float4*)(pp + 4);
                        a[0] += v0.x; a[1] += v0.y; a[2] += v0.z; a[3] += v0.w;
                        a[4] += v1.x; a[5] += v1.y; a[6] += v1.z; a[7] += v1.w;
                    }
            }
            float inv = 1.0f / (3.0f * (float)(cnt > 0 ? cnt : 1));
#pragma unroll
            for (int u = 0; u < 8; u++) r[u] = (_Float16)(a[u] * inv);
        } else {
            int ci = cap_inds[bw];
#pragma unroll
            for (int u = 0; u < 8; u++) {
                int c = (d8 - 96) * 8 + u;
                r[u] = (c < CAP_DIM) ? (_Float16)cap_table[ci * CAP_DIM + c] : (_Float16)0.f;
            }
        }
        *(f16x8*)(x + (size_t)bw * KPAD + d8 * 8) = r;
        __threadfence();                 // each thread's stores device-visible
        __syncthreads();
        if (t == 0)
            __hip_atomic_fetch_add(&cnts[b * 8 + g], 1, __ATOMIC_RELEASE,
                                   __HIP_MEMORY_SCOPE_AGENT);
        return;
    }

    // ===================== consumer (R11-proven fused gemm+LSTM) ============
    int dir  = blk >> 6;
    int b    = blk & 63;
    int wv   = t >> 6;
    int lane = t & 63;

    // gemm-side constants (waves 1-4)
    int mtile = wv - 1;
    int col   = lane & 15;
    int koff  = (lane >> 4) * 8;
    const _Float16* bp = wp + (size_t)(dir * G4 + col) * KPAD + koff;
    float bias_v[5];
    if (wv >= 1 && wv <= 4) {
#pragma unroll
        for (int nf = 0; nf < 5; nf++)
            bias_v[nf] = (dir ? bias_b : bias_f)[nf * 16 + col];
    }

    // recurrence-side constants (wave 0)
    const float* whh = dir ? whh_b : whh_f;
    int j = lane & 31; if (j > 19) j = 19;
    bool low = lane < 32;
    float mm = low ? 1.f : 2.f;
    float aa = low ? 0.f : -1.f;
    int coff = low ? (40 + 2 * j) : (2 * j);
    float w0[HH], w1[HH];
    if (wv == 0) {
        int r0 = low ? (20 + j) : j;
        int r1 = low ? (60 + j) : (40 + j);
#pragma unroll
        for (int k = 0; k < HH; k++) {
            w0[k] = whh[r0 * HH + k];
            w1[k] = whh[r1 * HH + k];
        }
    }

#define WAIT_CHUNK(CH) do {                                                     \
    int ga = dir ? (6 - 2 * (CH)) : (2 * (CH));                                 \
    waitc(cnts, b * 8 + ga);                                                    \
    waitc(cnts, b * 8 + ga + 1);                                                \
    __builtin_amdgcn_fence(__ATOMIC_ACQUIRE, "agent");                          \
} while (0)

#define COMPUTE_CHUNK(CH, BUF) do {                                             \
    int base_w = dir ? (192 - (CH) * 64) : (CH) * 64;                           \
    int arow = b * 256 + base_w + mtile * 16 + (lane & 15);                     \
    const _Float16* ap = x + (size_t)arow * KPAD + koff;                        \
    f32x4 acc[5];                                                               \
    _Pragma("unroll")                                                           \
    for (int nf = 0; nf < 5; nf++)                                              \
        _Pragma("unroll")                                                       \
        for (int r = 0; r < 4; r++) acc[nf][r] = 0.f;                           \
    for (int k0 = 0; k0 < KPAD; k0 += 32) {                                     \
        f16x8 af = *(const f16x8*)(ap + k0);                                    \
        _Pragma("unroll")                                                       \
        for (int nf = 0; nf < 5; nf++) {                                        \
            f16x8 bf = *(const f16x8*)(bp + (size_t)nf * 16 * KPAD + k0);       \
            acc[nf] = __builtin_amdgcn_mfma_f32_16x16x32_f16(af, bf, acc[nf], 0, 0, 0); \
        }                                                                       \
    }                                                                           \
    int lrow = mtile * 16 + (lane >> 4) * 4;                                    \
    _Pragma("unroll")                                                           \
    for (int nf = 0; nf < 5; nf++) {                                            \
        int g = nf * 16 + col;                                                  \
        int pcol = (g % 40) * 2 + (g / 40);                                     \
        _Pragma("unroll")                                                       \
        for (int r = 0; r < 4; r++)                                             \
            gbuf[BUF][(lrow + r) * G4 + pcol] = acc[nf][r] + bias_v[nf];        \
    }                                                                           \
} while (0)

    if (wv >= 1 && wv <= 4) { WAIT_CHUNK(0); COMPUTE_CHUNK(0, 0); }
    __syncthreads();

    float h = 0.f, c = 0.f;
    int w = dir ? (WW - 1) : 0;
    int stepd = dir ? -1 : 1;

    for (int ch = 0; ch < 4; ++ch) {
        int cb = ch & 1;
        if (wv >= 1 && wv <= 4) {
            if (ch + 1 < 4) { WAIT_CHUNK(ch + 1); COMPUTE_CHUNK(ch + 1, cb ^ 1); }
        } else if (wv == 0) {
            __builtin_amdgcn_s_setprio(1);
            int base = dir ? (192 - ch * 64) : ch * 64;
            float2 pre = *(const float2*)(&gbuf[cb][(w - base) * G4 + coff]);
            for (int sl = 0; sl < 64; ++sl) {
                int wn = w + stepd;
                float2 nxt = make_float2(0.f, 0.f);
                if (sl < 63)
                    nxt = *(const float2*)(&gbuf[cb][(wn - base) * G4 + coff]);
                float a0a = pre.x, a0b = 0.f, a1a = pre.y, a1b = 0.f;
#pragma unroll
                for (int k = 0; k < 10; k++) {
                    float hk  = __uint_as_float(__builtin_amdgcn_readlane(__float_as_uint(h), k));
                    float hk2 = __uint_as_float(__builtin_amdgcn_readlane(__float_as_uint(h), k + 10));
                    a0a = fmaf(hk,  w0[k],      a0a);
                    a1a = fmaf(hk,  w1[k],      a1a);
                    a0b = fmaf(hk2, w0[k + 10], a0b);
                    a1b = fmaf(hk2, w1[k + 10], a1b);
                }
                float a0 = a0a + a0b, a1 = a1a + a1b;
                float u0 = 1.f / (1.f + __expf(-a0));          // sig(f) | sig(i)
                float uu = 1.f / (1.f + __expf(-mm * a1));
                float u1 = fmaf(uu, mm, aa);                   // sig(o) | tanh(g)
                float p  = u0 * u1;
                float ps = xchg32(p);                          // low gets sig(i)*tanh(g)
                c = fmaf(u0, c, ps);
                float tc = fmaf(2.f, 1.f / (1.f + __expf(-2.f * c)), -1.f);
                h = u1 * tc;
                if (lane < HH)
                    out[((size_t)b * WW + w) * (2 * HH) + dir * HH + lane] = h;
                pre = nxt;
                w = wn;
            }
            __builtin_amdgcn_s_setprio(0);
        }
        __syncthreads();
    }
#undef COMPUTE_CHUNK
#undef WAIT_CHUNK
}

extern "C" void kernel_launch(void* const* d_in, const int* in_sizes, int n_in,
                              void* d_out, int out_size, void* d_ws, size_t ws_size,
                              hipStream_t stream) {
    const float* hiddens   = (const float*)d_in[0];
    const int*   bert2toks = (const int*)d_in[1];
    const int*   cap_inds  = (const int*)d_in[2];
    const float* cap_table = (const float*)d_in[3];
    const float* w_ih_f    = (const float*)d_in[4];
    const float* w_hh_f    = (const float*)d_in[5];
    const float* b_f       = (const float*)d_in[6];
    const float* w_ih_b    = (const float*)d_in[7];
    const float* w_hh_b    = (const float*)d_in[8];
    const float* b_b       = (const float*)d_in[9];
    float* out = (float*)d_out;

    _Float16* wpad = (_Float16*)((char*)d_ws + WP_OFF);
    int2*     seg  = (int2*)((char*)d_ws + SEG_OFF);
    int*      cnts = (int*)((char*)d_ws + CT_OFF);
    _Float16* x    = (_Float16*)((char*)d_ws + X_OFF);

    hipMemsetAsync(cnts, 0, 512 * sizeof(int), stream);
    k_prep<<<NOUT + BB, 256, 0, stream>>>(w_ih_f, w_ih_b, bert2toks, wpad, seg);
    k_mega<<<NCONS + NPRODB, 640, 0, stream>>>(hiddens, seg, cap_inds, cap_table,
                                               wpad, b_f, b_b, w_hh_f, w_hh_b,
                                               x, cnts, out);
}

// Round 16
// 259.138 us; speedup vs baseline: 4.8510x; 4.8510x over previous
//
#include <hip/hip_runtime.h>
#include <math.h>

#define BB 64
#define T_SUB 512
#define WW 256
#define DD 768
#define HH 20
#define CAP_DIM 10
#define IN_DIM 778
#define KPAD 800
#define G4 80     // 4*H
#define NOUT 160

#define NCONS 128    // consumer blocks (2 dir x 64 b), dispatched FIRST
#define NPRODB 2560  // producer blocks: 8 slots x 64 b x 5 sub (640 thr each)

typedef _Float16 f16x8 __attribute__((ext_vector_type(8)));
typedef float f32x4 __attribute__((ext_vector_type(4)));
typedef unsigned int uint2v __attribute__((ext_vector_type(2)));

// ws layout (bytes):
//   wpad : [160][800] f16   @ 0          (256,000 B)
//   seg  : int2[16384]      @ 256,000    (131,072 B)
//   cnts : int[512]         @ 387,072    (2,048 B)   -- zeroed each call
//   x    : [16384][800] f16 @ 389,120    (26,214,400 B)
#define WP_OFF   ((size_t)0)
#define SEG_OFF  ((size_t)256000)
#define CT_OFF   ((size_t)387072)
#define X_OFF    ((size_t)389120)

// ---------------- K0: pad weights (blocks 0..159) + segment search (160..223)
__global__ __launch_bounds__(256) void k_prep(
    const float* __restrict__ wf, const float* __restrict__ wb,
    const int* __restrict__ b2t,
    _Float16* __restrict__ wp, int2* __restrict__ seg)
{
    int blk = blockIdx.x;
    if (blk < NOUT) {
        int j = blk;
        const float* src = (j < G4) ? (wf + (size_t)j * IN_DIM)
                                    : (wb + (size_t)(j - G4) * IN_DIM);
        for (int k = threadIdx.x; k < KPAD; k += 256)
            wp[(size_t)j * KPAD + k] = (k < IN_DIM) ? (_Float16)src[k] : (_Float16)0.f;
    } else {
        int b = blk - NOUT, w = threadIdx.x;
        const int* row = b2t + (size_t)b * T_SUB;
        int lo = 0, hi = T_SUB;
        while (lo < hi) { int m = (lo + hi) >> 1; if (row[m] < w) lo = m + 1; else hi = m; }
        int lo2 = lo, hi2 = T_SUB;
        while (lo2 < hi2) { int m = (lo2 + hi2) >> 1; if (row[m] < w + 1) lo2 = m + 1; else hi2 = m; }
        seg[(size_t)b * WW + w] = make_int2(lo, lo2 - lo);
    }
}

// SYSTEM-scope relaxed poll: reads L3 directly, no L1/L2 invalidate per poll.
__device__ __forceinline__ void waitc(const int* cnts, int idx) {
    int it = 0;
    while (__hip_atomic_load(&cnts[idx], __ATOMIC_RELAXED,
                             __HIP_MEMORY_SCOPE_SYSTEM) < 5) {
        __builtin_amdgcn_s_sleep(4);
        if (++it > 3000000) break;   // failsafe
    }
}

__device__ __forceinline__ float xchg32(float v) {
    unsigned int a = __float_as_uint(v);
    uint2v r = __builtin_amdgcn_permlane32_swap(a, a, false, false);
    return __uint_as_float(r[0] ^ r[1] ^ a);   // partner lane's value (lane ^ 32)
}

// ---------------- K1: overlapped mega-kernel, 640-thread blocks -------------
// blocks 0..127    : consumers — R11-proven fused gemm+LSTM.
// blocks 128..2687 : producers — R11-proven k_mean, 1 item/thread; x published
//                    via L3 (system-scope stores), flag via relaxed system add.
//                    NO threadfence/wbl2 anywhere (R15's 18x collapse).
__global__ __launch_bounds__(640) void k_mega(
    const float* __restrict__ hiddens, const int2* __restrict__ seg,
    const int* __restrict__ cap_inds, const float* __restrict__ cap_table,
    const _Float16* __restrict__ wp,
    const float* __restrict__ bias_f, const float* __restrict__ bias_b,
    const float* __restrict__ whh_f, const float* __restrict__ whh_b,
    _Float16* __restrict__ x, int* __restrict__ cnts,
    float* __restrict__ out)
{
    __shared__ float gbuf[2][64 * G4];   // 40 KB (consumer ping-pong)
    int blk = blockIdx.x;
    int t = threadIdx.x;

    if (blk >= NCONS) {
        // ===================== producer =====================
        const int ORDER[8] = {0, 1, 6, 7, 2, 3, 4, 5};
        int p = blk - NCONS;
        int s = p / 320, q = p % 320;
        int b = q / 5, sub = q % 5;
        int g = ORDER[s];
        int i = sub * 640 + t;           // 0..3199 within group
        int row = i / 100, d8 = i % 100;
        int bw = b * WW + g * 32 + row;
        f16x8 r;
        if (d8 < 96) {
            int2 sg = seg[bw];
            int lo = sg.x, cnt = sg.y;
            const size_t LSTR = (size_t)BB * (T_SUB + 1) * DD;
            const float* base = hiddens + ((size_t)b * (T_SUB + 1) + lo + 1) * DD + d8 * 8;
            float a[8];
#pragma unroll
            for (int u = 0; u < 8; u++) a[u] = 0.f;
            if (cnt == 2) {
#pragma unroll
                for (int l = 0; l < 3; ++l) {
                    float4 v0 = *(const float4*)(base + l * LSTR);
                    float4 v1 = *(const float4*)(base + l * LSTR + 4);
                    float4 v2 = *(const float4*)(base + l * LSTR + DD);
                    float4 v3 = *(const float4*)(base + l * LSTR + DD + 4);
                    a[0] += v0.x + v2.x; a[1] += v0.y + v2.y;
                    a[2] += v0.z + v2.z; a[3] += v0.w + v2.w;
                    a[4] += v1.x + v3.x; a[5] += v1.y + v3.y;
                    a[6] += v1.z + v3.z; a[7] += v1.w + v3.w;
                }
            } else {
                for (int l = 0; l < 3; ++l)
                    for (int ti = 0; ti < cnt; ++ti) {
                        const float* pp = base + l * LSTR + (size_t)ti * DD;
                        float4 v0 = *(const float4*)(pp);
                        float4 v1 = *(const float4*)(pp + 4);
                        a[0] += v0.x; a[1] += v0.y; a[2] += v0.z; a[3] += v0.w;
                        a[4] += v1.x; a[5] += v1.y; a[6] += v1.z; a[7] += v1.w;
                    }
            }
            float inv = 1.0f / (3.0f * (float)(cnt > 0 ? cnt : 1));
#pragma unroll
            for (int u = 0; u < 8; u++) r[u] = (_Float16)(a[u] * inv);
        } else {
            int ci = cap_inds[bw];
#pragma unroll
            for (int u = 0; u < 8; u++) {
                int c = (d8 - 96) * 8 + u;
                r[u] = (c < CAP_DIM) ? (_Float16)cap_table[ci * CAP_DIM + c] : (_Float16)0.f;
            }
        }
        // publish x via L3 (system-scope relaxed dword stores: sc0 sc1, no wbl2)
        {
            union { f16x8 h; unsigned int u[4]; } cv; cv.h = r;
            unsigned int* xp = (unsigned int*)(x + (size_t)bw * KPAD + d8 * 8);
#pragma unroll
            for (int u_ = 0; u_ < 4; u_++)
                __hip_atomic_store(&xp[u_], cv.u[u_], __ATOMIC_RELAXED,
                                   __HIP_MEMORY_SCOPE_SYSTEM);
        }
        asm volatile("s_waitcnt vmcnt(0)" ::: "memory");   // stores ack'd at L3
        __syncthreads();                                   // all waves done
        if (t == 0)
            __hip_atomic_fetch_add(&cnts[b * 8 + g], 1, __ATOMIC_RELAXED,
                                   __HIP_MEMORY_SCOPE_SYSTEM);
        return;
    }

    // ===================== consumer (R11-proven fused gemm+LSTM) ============
    int dir  = blk >> 6;
    int b    = blk & 63;
    int wv   = t >> 6;
    int lane = t & 63;

    // gemm-side constants (waves 1-4)
    int mtile = wv - 1;
    int col   = lane & 15;
    int koff  = (lane >> 4) * 8;
    const _Float16* bp = wp + (size_t)(dir * G4 + col) * KPAD + koff;
    float bias_v[5];
    if (wv >= 1 && wv <= 4) {
#pragma unroll
        for (int nf = 0; nf < 5; nf++)
            bias_v[nf] = (dir ? bias_b : bias_f)[nf * 16 + col];
    }

    // recurrence-side constants (wave 0)
    const float* whh = dir ? whh_b : whh_f;
    int j = lane & 31; if (j > 19) j = 19;
    bool low = lane < 32;
    float mm = low ? 1.f : 2.f;
    float aa = low ? 0.f : -1.f;
    int coff = low ? (40 + 2 * j) : (2 * j);
    float w0[HH], w1[HH];
    if (wv == 0) {
        int r0 = low ? (20 + j) : j;
        int r1 = low ? (60 + j) : (40 + j);
#pragma unroll
        for (int k = 0; k < HH; k++) {
            w0[k] = whh[r0 * HH + k];
            w1[k] = whh[r1 * HH + k];
        }
    }

#define WAIT_CHUNK(CH) do {                                                     \
    int ga = dir ? (6 - 2 * (CH)) : (2 * (CH));                                 \
    waitc(cnts, b * 8 + ga);                                                    \
    waitc(cnts, b * 8 + ga + 1);                                                \
    __builtin_amdgcn_fence(__ATOMIC_ACQUIRE, "agent");  /* inv L1/L2 once */    \
} while (0)

#define COMPUTE_CHUNK(CH, BUF) do {                                             \
    int base_w = dir ? (192 - (CH) * 64) : (CH) * 64;                           \
    int arow = b * 256 + base_w + mtile * 16 + (lane & 15);                     \
    const _Float16* ap = x + (size_t)arow * KPAD + koff;                        \
    f32x4 acc[5];                                                               \
    _Pragma("unroll")                                                           \
    for (int nf = 0; nf < 5; nf++)                                              \
        _Pragma("unroll")                                                       \
        for (int r = 0; r < 4; r++) acc[nf][r] = 0.f;                           \
    for (int k0 = 0; k0 < KPAD; k0 += 32) {                                     \
        f16x8 af = *(const f16x8*)(ap + k0);                                    \
        _Pragma("unroll")                                                       \
        for (int nf = 0; nf < 5; nf++) {                                        \
            f16x8 bf = *(const f16x8*)(bp + (size_t)nf * 16 * KPAD + k0);       \
            acc[nf] = __builtin_amdgcn_mfma_f32_16x16x32_f16(af, bf, acc[nf], 0, 0, 0); \
        }                                                                       \
    }                                                                           \
    int lrow = mtile * 16 + (lane >> 4) * 4;                                    \
    _Pragma("unroll")                                                           \
    for (int nf = 0; nf < 5; nf++) {                                            \
        int g = nf * 16 + col;                                                  \
        int pcol = (g % 40) * 2 + (g / 40);                                     \
        _Pragma("unroll")                                                       \
        for (int r = 0; r < 4; r++)                                             \
            gbuf[BUF][(lrow + r) * G4 + pcol] = acc[nf][r] + bias_v[nf];        \
    }                                                                           \
} while (0)

    if (wv >= 1 && wv <= 4) { WAIT_CHUNK(0); COMPUTE_CHUNK(0, 0); }
    __syncthreads();

    float h = 0.f, c = 0.f;
    int w = dir ? (WW - 1) : 0;
    int stepd = dir ? -1 : 1;

    for (int ch = 0; ch < 4; ++ch) {
        int cb = ch & 1;
        if (wv >= 1 && wv <= 4) {
            if (ch + 1 < 4) { WAIT_CHUNK(ch + 1); COMPUTE_CHUNK(ch + 1, cb ^ 1); }
        } else if (wv == 0) {
            __builtin_amdgcn_s_setprio(1);
            int base = dir ? (192 - ch * 64) : ch * 64;
            float2 pre = *(const float2*)(&gbuf[cb][(w - base) * G4 + coff]);
            for (int sl = 0; sl < 64; ++sl) {
                int wn = w + stepd;
                float2 nxt = make_float2(0.f, 0.f);
                if (sl < 63)
                    nxt = *(const float2*)(&gbuf[cb][(wn - base) * G4 + coff]);
                float a0a = pre.x, a0b = 0.f, a1a = pre.y, a1b = 0.f;
#pragma unroll
                for (int k = 0; k < 10; k++) {
                    float hk  = __uint_as_float(__builtin_amdgcn_readlane(__float_as_uint(h), k));
                    float hk2 = __uint_as_float(__builtin_amdgcn_readlane(__float_as_uint(h), k + 10));
                    a0a = fmaf(hk,  w0[k],      a0a);
                    a1a = fmaf(hk,  w1[k],      a1a);
                    a0b = fmaf(hk2, w0[k + 10], a0b);
                    a1b = fmaf(hk2, w1[k + 10], a1b);
                }
                float a0 = a0a + a0b, a1 = a1a + a1b;
                float u0 = 1.f / (1.f + __expf(-a0));          // sig(f) | sig(i)
                float uu = 1.f / (1.f + __expf(-mm * a1));
                float u1 = fmaf(uu, mm, aa);                   // sig(o) | tanh(g)
                float p  = u0 * u1;
                float ps = xchg32(p);                          // low gets sig(i)*tanh(g)
                c = fmaf(u0, c, ps);
                float tc = fmaf(2.f, 1.f / (1.f + __expf(-2.f * c)), -1.f);
                h = u1 * tc;
                if (lane < HH)
                    out[((size_t)b * WW + w) * (2 * HH) + dir * HH + lane] = h;
                pre = nxt;
                w = wn;
            }
            __builtin_amdgcn_s_setprio(0);
        }
        __syncthreads();
    }
#undef COMPUTE_CHUNK
#undef WAIT_CHUNK
}

extern "C" void kernel_launch(void* const* d_in, const int* in_sizes, int n_in,
                              void* d_out, int out_size, void* d_ws, size_t ws_size,
                              hipStream_t stream) {
    const float* hiddens   = (const float*)d_in[0];
    const int*   bert2toks = (const int*)d_in[1];
    const int*   cap_inds  = (const int*)d_in[2];
    const float* cap_table = (const float*)d_in[3];
    const float* w_ih_f    = (const float*)d_in[4];
    const float* w_hh_f    = (const float*)d_in[5];
    const float* b_f       = (const float*)d_in[6];
    const float* w_ih_b    = (const float*)d_in[7];
    const float* w_hh_b    = (const float*)d_in[8];
    const float* b_b       = (const float*)d_in[9];
    float* out = (float*)d_out;

    _Float16* wpad = (_Float16*)((char*)d_ws + WP_OFF);
    int2*     seg  = (int2*)((char*)d_ws + SEG_OFF);
    int*      cnts = (int*)((char*)d_ws + CT_OFF);
    _Float16* x    = (_Float16*)((char*)d_ws + X_OFF);

    hipMemsetAsync(cnts, 0, 512 * sizeof(int), stream);
    k_prep<<<NOUT + BB, 256, 0, stream>>>(w_ih_f, w_ih_b, bert2toks, wpad, seg);
    k_mega<<<NCONS + NPRODB, 640, 0, stream>>>(hiddens, seg, cap_inds, cap_table,
                                               wpad, b_f, b_b, w_hh_f, w_hh_b,
                                               x, cnts, out);
}

// Round 17
// 160.207 us; speedup vs baseline: 7.8466x; 1.6175x over previous
//
#include <hip/hip_runtime.h>
#include <math.h>

#define BB 64
#define T_SUB 512
#define WW 256
#define DD 768
#define HH 20
#define CAP_DIM 10
#define IN_DIM 778
#define KPAD 800
#define G4 80     // 4*H
#define NOUT 160

typedef _Float16 f16x8 __attribute__((ext_vector_type(8)));
typedef float f32x4 __attribute__((ext_vector_type(4)));
typedef unsigned int uint2v __attribute__((ext_vector_type(2)));

// ws layout (bytes):
//   wpad : [160][800] f16   @ 0          (256,000 B)
//   seg  : int2[16384]      @ 256,000    (131,072 B)
//   x    : [16384][800] f16 @ 387,072    (26,214,400 B)
#define WP_OFF   ((size_t)0)
#define SEG_OFF  ((size_t)256000)
#define X_OFF    ((size_t)387072)

// ---------------- K0: pad weights (blocks 0..159) + segment search (160..223)
__global__ __launch_bounds__(256) void k_prep(
    const float* __restrict__ wf, const float* __restrict__ wb,
    const int* __restrict__ b2t,
    _Float16* __restrict__ wp, int2* __restrict__ seg)
{
    int blk = blockIdx.x;
    if (blk < NOUT) {
        int j = blk;
        const float* src = (j < G4) ? (wf + (size_t)j * IN_DIM)
                                    : (wb + (size_t)(j - G4) * IN_DIM);
        for (int k = threadIdx.x; k < KPAD; k += 256)
            wp[(size_t)j * KPAD + k] = (k < IN_DIM) ? (_Float16)src[k] : (_Float16)0.f;
    } else {
        int b = blk - NOUT, w = threadIdx.x;
        const int* row = b2t + (size_t)b * T_SUB;
        int lo = 0, hi = T_SUB;
        while (lo < hi) { int m = (lo + hi) >> 1; if (row[m] < w) lo = m + 1; else hi = m; }
        int lo2 = lo, hi2 = T_SUB;
        while (lo2 < hi2) { int m = (lo2 + hi2) >> 1; if (row[m] < w + 1) lo2 = m + 1; else hi2 = m; }
        seg[(size_t)b * WW + w] = make_int2(lo, lo2 - lo);
    }
}

// ---------------- K1: streaming mean -> fp16 x. TWO d8-items per thread -----
// Thread handles (bw, d2) and (bw, d2+50): same word -> one seg read, and in
// the cnt==2 fast path all 24 float4 loads are in flight before any use
// (384 B/lane outstanding -> covers ~900cy HBM latency at 30 waves/CU).
__global__ __launch_bounds__(256) void k_mean(
    const float* __restrict__ hiddens, const int2* __restrict__ seg,
    const int* __restrict__ cap_inds, const float* __restrict__ cap_table,
    _Float16* __restrict__ x)
{
    int idx = blockIdx.x * 256 + threadIdx.x;   // 16384*50 total
    int d2 = idx % 50;
    int bw = idx / 50;
    int b = bw >> 8;
    int2 sg = seg[bw];
    int lo = sg.x, cnt = sg.y;
    const size_t LSTR = (size_t)BB * (T_SUB + 1) * DD;
    const float* rowp = hiddens + ((size_t)b * (T_SUB + 1) + lo + 1) * DD;
    float inv = 1.0f / (3.0f * (float)(cnt > 0 ? cnt : 1));
    bool bmean = (d2 + 50) < 96;                // item B is a mean item
    f16x8 ra, rb;

    if (cnt == 2 && bmean) {
        const float* pa  = rowp + d2 * 8;
        const float* pb_ = rowp + (d2 + 50) * 8;
        float4 A0 = *(const float4*)(pa);                float4 A1 = *(const float4*)(pa + 4);
        float4 A2 = *(const float4*)(pa + DD);           float4 A3 = *(const float4*)(pa + DD + 4);
        float4 A4 = *(const float4*)(pa + LSTR);         float4 A5 = *(const float4*)(pa + LSTR + 4);
        float4 A6 = *(const float4*)(pa + LSTR + DD);    float4 A7 = *(const float4*)(pa + LSTR + DD + 4);
        float4 A8 = *(const float4*)(pa + 2*LSTR);       float4 A9 = *(const float4*)(pa + 2*LSTR + 4);
        float4 Aa = *(const float4*)(pa + 2*LSTR + DD);  float4 Ab = *(const float4*)(pa + 2*LSTR + DD + 4);
        float4 B0 = *(const float4*)(pb_);               float4 B1 = *(const float4*)(pb_ + 4);
        float4 B2 = *(const float4*)(pb_ + DD);          float4 B3 = *(const float4*)(pb_ + DD + 4);
        float4 B4 = *(const float4*)(pb_ + LSTR);        float4 B5 = *(const float4*)(pb_ + LSTR + 4);
        float4 B6 = *(const float4*)(pb_ + LSTR + DD);   float4 B7 = *(const float4*)(pb_ + LSTR + DD + 4);
        float4 B8 = *(const float4*)(pb_ + 2*LSTR);      float4 B9 = *(const float4*)(pb_ + 2*LSTR + 4);
        float4 Ba = *(const float4*)(pb_ + 2*LSTR + DD); float4 Bb = *(const float4*)(pb_ + 2*LSTR + DD + 4);
        ra[0] = (_Float16)((A0.x+A2.x+A4.x+A6.x+A8.x+Aa.x) * inv);
        ra[1] = (_Float16)((A0.y+A2.y+A4.y+A6.y+A8.y+Aa.y) * inv);
        ra[2] = (_Float16)((A0.z+A2.z+A4.z+A6.z+A8.z+Aa.z) * inv);
        ra[3] = (_Float16)((A0.w+A2.w+A4.w+A6.w+A8.w+Aa.w) * inv);
        ra[4] = (_Float16)((A1.x+A3.x+A5.x+A7.x+A9.x+Ab.x) * inv);
        ra[5] = (_Float16)((A1.y+A3.y+A5.y+A7.y+A9.y+Ab.y) * inv);
        ra[6] = (_Float16)((A1.z+A3.z+A5.z+A7.z+A9.z+Ab.z) * inv);
        ra[7] = (_Float16)((A1.w+A3.w+A5.w+A7.w+A9.w+Ab.w) * inv);
        rb[0] = (_Float16)((B0.x+B2.x+B4.x+B6.x+B8.x+Ba.x) * inv);
        rb[1] = (_Float16)((B0.y+B2.y+B4.y+B6.y+B8.y+Ba.y) * inv);
        rb[2] = (_Float16)((B0.z+B2.z+B4.z+B6.z+B8.z+Ba.z) * inv);
        rb[3] = (_Float16)((B0.w+B2.w+B4.w+B6.w+B8.w+Ba.w) * inv);
        rb[4] = (_Float16)((B1.x+B3.x+B5.x+B7.x+B9.x+Bb.x) * inv);
        rb[5] = (_Float16)((B1.y+B3.y+B5.y+B7.y+B9.y+Bb.y) * inv);
        rb[6] = (_Float16)((B1.z+B3.z+B5.z+B7.z+B9.z+Bb.z) * inv);
        rb[7] = (_Float16)((B1.w+B3.w+B5.w+B7.w+B9.w+Bb.w) * inv);
    } else {
        float a[8], bacc[8];
#pragma unroll
        for (int q = 0; q < 8; q++) { a[q] = 0.f; bacc[q] = 0.f; }
        for (int l = 0; l < 3; ++l)
            for (int ti = 0; ti < cnt; ++ti) {
                const float* p = rowp + l * LSTR + (size_t)ti * DD;
                float4 v0 = *(const float4*)(p + d2 * 8);
                float4 v1 = *(const float4*)(p + d2 * 8 + 4);
                a[0]+=v0.x; a[1]+=v0.y; a[2]+=v0.z; a[3]+=v0.w;
                a[4]+=v1.x; a[5]+=v1.y; a[6]+=v1.z; a[7]+=v1.w;
                if (bmean) {
                    float4 u0 = *(const float4*)(p + (d2 + 50) * 8);
                    float4 u1 = *(const float4*)(p + (d2 + 50) * 8 + 4);
                    bacc[0]+=u0.x; bacc[1]+=u0.y; bacc[2]+=u0.z; bacc[3]+=u0.w;
                    bacc[4]+=u1.x; bacc[5]+=u1.y; bacc[6]+=u1.z; bacc[7]+=u1.w;
                }
            }
#pragma unroll
        for (int q = 0; q < 8; q++) { ra[q] = (_Float16)(a[q] * inv); rb[q] = (_Float16)(bacc[q] * inv); }
    }
    if (!bmean) {   // item B is caps/pad (d8 in 96..99)
        int ci = cap_inds[bw];
#pragma unroll
        for (int q = 0; q < 8; q++) {
            int c = (d2 + 50 - 96) * 8 + q;
            rb[q] = (c < CAP_DIM) ? (_Float16)cap_table[ci * CAP_DIM + c] : (_Float16)0.f;
        }
    }
    *(f16x8*)(x + (size_t)bw * KPAD + d2 * 8) = ra;
    *(f16x8*)(x + (size_t)bw * KPAD + (d2 + 50) * 8) = rb;
}

// ---------------- K2: FUSED gemm+LSTM (R11-proven) + setprio ----------------
__device__ __forceinline__ float xchg32(float v) {
    unsigned int a = __float_as_uint(v);
    uint2v r = __builtin_amdgcn_permlane32_swap(a, a, false, false);
    return __uint_as_float(r[0] ^ r[1] ^ a);   // partner lane's value (lane ^ 32)
}

__global__ __launch_bounds__(320) void k_lstm(
    const _Float16* __restrict__ x, const _Float16* __restrict__ wp,
    const float* __restrict__ bias_f, const float* __restrict__ bias_b,
    const float* __restrict__ whh_f, const float* __restrict__ whh_b,
    float* __restrict__ out)
{
    __shared__ float gbuf[2][64 * G4];   // 2 x 20 KB ping-pong (permuted cols)
    int dir  = blockIdx.x >> 6;
    int b    = blockIdx.x & 63;
    int t    = threadIdx.x;
    int wv   = t >> 6;
    int lane = t & 63;

    // gemm-side constants (waves 1-4)
    int mtile = wv - 1;
    int col   = lane & 15;
    int koff  = (lane >> 4) * 8;
    const _Float16* bp = wp + (size_t)(dir * G4 + col) * KPAD + koff;
    float bias_v[5];
    if (wv > 0) {
#pragma unroll
        for (int nf = 0; nf < 5; nf++)
            bias_v[nf] = (dir ? bias_b : bias_f)[nf * 16 + col];
    }

    // recurrence-side constants (wave 0)
    const float* whh = dir ? whh_b : whh_f;
    int j = lane & 31; if (j > 19) j = 19;
    bool low = lane < 32;
    float mm = low ? 1.f : 2.f;
    float aa = low ? 0.f : -1.f;
    int coff = low ? (40 + 2 * j) : (2 * j);
    float w0[HH], w1[HH];
    if (wv == 0) {
        int r0 = low ? (20 + j) : j;
        int r1 = low ? (60 + j) : (40 + j);
#pragma unroll
        for (int k = 0; k < HH; k++) {
            w0[k] = whh[r0 * HH + k];
            w1[k] = whh[r1 * HH + k];
        }
    }

#define COMPUTE_CHUNK(CH, BUF) do {                                             \
    int base_w = dir ? (192 - (CH) * 64) : (CH) * 64;                           \
    int arow = b * 256 + base_w + mtile * 16 + (lane & 15);                     \
    const _Float16* ap = x + (size_t)arow * KPAD + koff;                        \
    f32x4 acc[5];                                                               \
    _Pragma("unroll")                                                           \
    for (int nf = 0; nf < 5; nf++)                                              \
        _Pragma("unroll")                                                       \
        for (int r = 0; r < 4; r++) acc[nf][r] = 0.f;                           \
    for (int k0 = 0; k0 < KPAD; k0 += 32) {                                     \
        f16x8 af = *(const f16x8*)(ap + k0);                                    \
        _Pragma("unroll")                                                       \
        for (int nf = 0; nf < 5; nf++) {                                        \
            f16x8 bf = *(const f16x8*)(bp + (size_t)nf * 16 * KPAD + k0);       \
            acc[nf] = __builtin_amdgcn_mfma_f32_16x16x32_f16(af, bf, acc[nf], 0, 0, 0); \
        }                                                                       \
    }                                                                           \
    int lrow = mtile * 16 + (lane >> 4) * 4;                                    \
    _Pragma("unroll")                                                           \
    for (int nf = 0; nf < 5; nf++) {                                            \
        int g = nf * 16 + col;                                                  \
        int pcol = (g % 40) * 2 + (g / 40);                                     \
        _Pragma("unroll")                                                       \
        for (int r = 0; r < 4; r++)                                             \
            gbuf[BUF][(lrow + r) * G4 + pcol] = acc[nf][r] + bias_v[nf];        \
    }                                                                           \
} while (0)

    if (wv > 0) COMPUTE_CHUNK(0, 0);
    __syncthreads();

    float h = 0.f, c = 0.f;
    int w = dir ? (WW - 1) : 0;
    int stepd = dir ? -1 : 1;

    for (int ch = 0; ch < 4; ++ch) {
        int cb = ch & 1;
        if (wv > 0) {
            if (ch + 1 < 4) COMPUTE_CHUNK(ch + 1, cb ^ 1);
        } else {
            __builtin_amdgcn_s_setprio(1);
            int base = dir ? (192 - ch * 64) : ch * 64;
            float2 pre = *(const float2*)(&gbuf[cb][(w - base) * G4 + coff]);
            for (int sl = 0; sl < 64; ++sl) {
                int wn = w + stepd;
                float2 nxt = make_float2(0.f, 0.f);
                if (sl < 63)
                    nxt = *(const float2*)(&gbuf[cb][(wn - base) * G4 + coff]);
                float a0a = pre.x, a0b = 0.f, a1a = pre.y, a1b = 0.f;
#pragma unroll
                for (int k = 0; k < 10; k++) {
                    float hk  = __uint_as_float(__builtin_amdgcn_readlane(__float_as_uint(h), k));
                    float hk2 = __uint_as_float(__builtin_amdgcn_readlane(__float_as_uint(h), k + 10));
                    a0a = fmaf(hk,  w0[k],      a0a);
                    a1a = fmaf(hk,  w1[k],      a1a);
                    a0b = fmaf(hk2, w0[k + 10], a0b);
                    a1b = fmaf(hk2, w1[k + 10], a1b);
                }
                float a0 = a0a + a0b, a1 = a1a + a1b;
                float u0 = 1.f / (1.f + __expf(-a0));          // sig(f) | sig(i)
                float uu = 1.f / (1.f + __expf(-mm * a1));
                float u1 = fmaf(uu, mm, aa);                   // sig(o) | tanh(g)
                float p  = u0 * u1;
                float ps = xchg32(p);                          // low gets sig(i)*tanh(g)
                c = fmaf(u0, c, ps);
                float tc = fmaf(2.f, 1.f / (1.f + __expf(-2.f * c)), -1.f);
                h = u1 * tc;
                if (lane < HH)
                    out[((size_t)b * WW + w) * (2 * HH) + dir * HH + lane] = h;
                pre = nxt;
                w = wn;
            }
            __builtin_amdgcn_s_setprio(0);
        }
        __syncthreads();
    }
#undef COMPUTE_CHUNK
}

extern "C" void kernel_launch(void* const* d_in, const int* in_sizes, int n_in,
                              void* d_out, int out_size, void* d_ws, size_t ws_size,
                              hipStream_t stream) {
    const float* hiddens   = (const float*)d_in[0];
    const int*   bert2toks = (const int*)d_in[1];
    const int*   cap_inds  = (const int*)d_in[2];
    const float* cap_table = (const float*)d_in[3];
    const float* w_ih_f    = (const float*)d_in[4];
    const float* w_hh_f    = (const float*)d_in[5];
    const float* b_f       = (const float*)d_in[6];
    const float* w_ih_b    = (const float*)d_in[7];
    const float* w_hh_b    = (const float*)d_in[8];
    const float* b_b       = (const float*)d_in[9];
    float* out = (float*)d_out;

    _Float16* wpad = (_Float16*)((char*)d_ws + WP_OFF);
    int2*     seg  = (int2*)((char*)d_ws + SEG_OFF);
    _Float16* x    = (_Float16*)((char*)d_ws + X_OFF);

    k_prep<<<NOUT + BB, 256, 0, stream>>>(w_ih_f, w_ih_b, bert2toks, wpad, seg);
    k_mean<<<(BB * WW * 50) / 256, 256, 0, stream>>>(hiddens, seg, cap_inds, cap_table, x);
    k_lstm<<<128, 320, 0, stream>>>(x, wpad, b_f, b_b, w_hh_f, w_hh_b, out);
}

// Round 18
// 156.242 us; speedup vs baseline: 8.0457x; 1.0254x over previous
//
#include <hip/hip_runtime.h>
#include <math.h>

#define BB 64
#define T_SUB 512
#define WW 256
#define DD 768
#define HH 20
#define CAP_DIM 10
#define IN_DIM 778
#define KPAD 800
#define G4 80     // 4*H
#define NOUT 160
#define LOG2E 1.44269504f

typedef _Float16 f16x8 __attribute__((ext_vector_type(8)));
typedef float f32x4 __attribute__((ext_vector_type(4)));
typedef unsigned int uint2v __attribute__((ext_vector_type(2)));

// ws layout (bytes):
//   wpad : [160][800] f16   @ 0          (256,000 B)  -- PRE-SCALED by log2e
//   seg  : int2[16384]      @ 256,000    (131,072 B)
//   x    : [16384][800] f16 @ 387,072    (26,214,400 B)
#define WP_OFF   ((size_t)0)
#define SEG_OFF  ((size_t)256000)
#define X_OFF    ((size_t)387072)

// ---------------- K0: pad+scale weights (0..159) + segment search (160..223)
__global__ __launch_bounds__(256) void k_prep(
    const float* __restrict__ wf, const float* __restrict__ wb,
    const int* __restrict__ b2t,
    _Float16* __restrict__ wp, int2* __restrict__ seg)
{
    int blk = blockIdx.x;
    if (blk < NOUT) {
        int j = blk;
        const float* src = (j < G4) ? (wf + (size_t)j * IN_DIM)
                                    : (wb + (size_t)(j - G4) * IN_DIM);
        for (int k = threadIdx.x; k < KPAD; k += 256)
            wp[(size_t)j * KPAD + k] = (k < IN_DIM) ? (_Float16)(LOG2E * src[k])
                                                    : (_Float16)0.f;
    } else {
        int b = blk - NOUT, w = threadIdx.x;
        const int* row = b2t + (size_t)b * T_SUB;
        int lo = 0, hi = T_SUB;
        while (lo < hi) { int m = (lo + hi) >> 1; if (row[m] < w) lo = m + 1; else hi = m; }
        int lo2 = lo, hi2 = T_SUB;
        while (lo2 < hi2) { int m = (lo2 + hi2) >> 1; if (row[m] < w + 1) lo2 = m + 1; else hi2 = m; }
        seg[(size_t)b * WW + w] = make_int2(lo, lo2 - lo);
    }
}

// ---------------- K1: streaming mean -> fp16 x (R17-proven, unchanged) ------
__global__ __launch_bounds__(256) void k_mean(
    const float* __restrict__ hiddens, const int2* __restrict__ seg,
    const int* __restrict__ cap_inds, const float* __restrict__ cap_table,
    _Float16* __restrict__ x)
{
    int idx = blockIdx.x * 256 + threadIdx.x;   // 16384*50 total
    int d2 = idx % 50;
    int bw = idx / 50;
    int b = bw >> 8;
    int2 sg = seg[bw];
    int lo = sg.x, cnt = sg.y;
    const size_t LSTR = (size_t)BB * (T_SUB + 1) * DD;
    const float* rowp = hiddens + ((size_t)b * (T_SUB + 1) + lo + 1) * DD;
    float inv = 1.0f / (3.0f * (float)(cnt > 0 ? cnt : 1));
    bool bmean = (d2 + 50) < 96;
    f16x8 ra, rb;

    if (cnt == 2 && bmean) {
        const float* pa  = rowp + d2 * 8;
        const float* pb_ = rowp + (d2 + 50) * 8;
        float4 A0 = *(const float4*)(pa);                float4 A1 = *(const float4*)(pa + 4);
        float4 A2 = *(const float4*)(pa + DD);           float4 A3 = *(const float4*)(pa + DD + 4);
        float4 A4 = *(const float4*)(pa + LSTR);         float4 A5 = *(const float4*)(pa + LSTR + 4);
        float4 A6 = *(const float4*)(pa + LSTR + DD);    float4 A7 = *(const float4*)(pa + LSTR + DD + 4);
        float4 A8 = *(const float4*)(pa + 2*LSTR);       float4 A9 = *(const float4*)(pa + 2*LSTR + 4);
        float4 Aa = *(const float4*)(pa + 2*LSTR + DD);  float4 Ab = *(const float4*)(pa + 2*LSTR + DD + 4);
        float4 B0 = *(const float4*)(pb_);               float4 B1 = *(const float4*)(pb_ + 4);
        float4 B2 = *(const float4*)(pb_ + DD);          float4 B3 = *(const float4*)(pb_ + DD + 4);
        float4 B4 = *(const float4*)(pb_ + LSTR);        float4 B5 = *(const float4*)(pb_ + LSTR + 4);
        float4 B6 = *(const float4*)(pb_ + LSTR + DD);   float4 B7 = *(const float4*)(pb_ + LSTR + DD + 4);
        float4 B8 = *(const float4*)(pb_ + 2*LSTR);      float4 B9 = *(const float4*)(pb_ + 2*LSTR + 4);
        float4 Ba = *(const float4*)(pb_ + 2*LSTR + DD); float4 Bb = *(const float4*)(pb_ + 2*LSTR + DD + 4);
        ra[0] = (_Float16)((A0.x+A2.x+A4.x+A6.x+A8.x+Aa.x) * inv);
        ra[1] = (_Float16)((A0.y+A2.y+A4.y+A6.y+A8.y+Aa.y) * inv);
        ra[2] = (_Float16)((A0.z+A2.z+A4.z+A6.z+A8.z+Aa.z) * inv);
        ra[3] = (_Float16)((A0.w+A2.w+A4.w+A6.w+A8.w+Aa.w) * inv);
        ra[4] = (_Float16)((A1.x+A3.x+A5.x+A7.x+A9.x+Ab.x) * inv);
        ra[5] = (_Float16)((A1.y+A3.y+A5.y+A7.y+A9.y+Ab.y) * inv);
        ra[6] = (_Float16)((A1.z+A3.z+A5.z+A7.z+A9.z+Ab.z) * inv);
        ra[7] = (_Float16)((A1.w+A3.w+A5.w+A7.w+A9.w+Ab.w) * inv);
        rb[0] = (_Float16)((B0.x+B2.x+B4.x+B6.x+B8.x+Ba.x) * inv);
        rb[1] = (_Float16)((B0.y+B2.y+B4.y+B6.y+B8.y+Ba.y) * inv);
        rb[2] = (_Float16)((B0.z+B2.z+B4.z+B6.z+B8.z+Ba.z) * inv);
        rb[3] = (_Float16)((B0.w+B2.w+B4.w+B6.w+B8.w+Ba.w) * inv);
        rb[4] = (_Float16)((B1.x+B3.x+B5.x+B7.x+B9.x+Bb.x) * inv);
        rb[5] = (_Float16)((B1.y+B3.y+B5.y+B7.y+B9.y+Bb.y) * inv);
        rb[6] = (_Float16)((B1.z+B3.z+B5.z+B7.z+B9.z+Bb.z) * inv);
        rb[7] = (_Float16)((B1.w+B3.w+B5.w+B7.w+B9.w+Bb.w) * inv);
    } else {
        float a[8], bacc[8];
#pragma unroll
        for (int q = 0; q < 8; q++) { a[q] = 0.f; bacc[q] = 0.f; }
        for (int l = 0; l < 3; ++l)
            for (int ti = 0; ti < cnt; ++ti) {
                const float* p = rowp + l * LSTR + (size_t)ti * DD;
                float4 v0 = *(const float4*)(p + d2 * 8);
                float4 v1 = *(const float4*)(p + d2 * 8 + 4);
                a[0]+=v0.x; a[1]+=v0.y; a[2]+=v0.z; a[3]+=v0.w;
                a[4]+=v1.x; a[5]+=v1.y; a[6]+=v1.z; a[7]+=v1.w;
                if (bmean) {
                    float4 u0 = *(const float4*)(p + (d2 + 50) * 8);
                    float4 u1 = *(const float4*)(p + (d2 + 50) * 8 + 4);
                    bacc[0]+=u0.x; bacc[1]+=u0.y; bacc[2]+=u0.z; bacc[3]+=u0.w;
                    bacc[4]+=u1.x; bacc[5]+=u1.y; bacc[6]+=u1.z; bacc[7]+=u1.w;
                }
            }
#pragma unroll
        for (int q = 0; q < 8; q++) { ra[q] = (_Float16)(a[q] * inv); rb[q] = (_Float16)(bacc[q] * inv); }
    }
    if (!bmean) {
        int ci = cap_inds[bw];
#pragma unroll
        for (int q = 0; q < 8; q++) {
            int c = (d2 + 50 - 96) * 8 + q;
            rb[q] = (c < CAP_DIM) ? (_Float16)cap_table[ci * CAP_DIM + c] : (_Float16)0.f;
        }
    }
    *(f16x8*)(x + (size_t)bw * KPAD + d2 * 8) = ra;
    *(f16x8*)(x + (size_t)bw * KPAD + (d2 + 50) * 8) = rb;
}

// ---------------- K2: FUSED gemm+LSTM, all-chunks-upfront, solo chain -------
// grid 128 (dir*64+b), block 320 (5 waves). Waves 1-4 each gemm one 64-word
// chunk into the f16 gate buffer (ALL 256 words, 40 KB LDS); ONE barrier;
// then waves 1-4 exit and wave 0 runs the 256-step chain solo (no barriers,
// no competing issue). Gates pre-scaled by log2e -> exp2f activations.
__device__ __forceinline__ float xchg32(float v) {
    unsigned int a = __float_as_uint(v);
    uint2v r = __builtin_amdgcn_permlane32_swap(a, a, false, false);
    return __uint_as_float(r[0] ^ r[1] ^ a);   // partner lane's value (lane ^ 32)
}

__global__ __launch_bounds__(320) void k_lstm(
    const _Float16* __restrict__ x, const _Float16* __restrict__ wp,
    const float* __restrict__ bias_f, const float* __restrict__ bias_b,
    const float* __restrict__ whh_f, const float* __restrict__ whh_b,
    float* __restrict__ out)
{
    __shared__ _Float16 gb[WW * G4];     // 40 KB: all 256 words' gates (f16)
    int dir  = blockIdx.x >> 6;
    int b    = blockIdx.x & 63;
    int t    = threadIdx.x;
    int wv   = t >> 6;
    int lane = t & 63;

    if (wv >= 1) {
        // ---- gemm: wave wv owns words [64*(wv-1), 64*wv), all 4 mtiles ----
        int col  = lane & 15;
        int koff = (lane >> 4) * 8;
        int wbase = (wv - 1) * 64;
        const _Float16* bp = wp + (size_t)(dir * G4 + col) * KPAD + koff;
        float bias_v[5];
#pragma unroll
        for (int nf = 0; nf < 5; nf++)
            bias_v[nf] = LOG2E * (dir ? bias_b : bias_f)[nf * 16 + col];
        f32x4 acc[4][5];
#pragma unroll
        for (int mt = 0; mt < 4; mt++)
#pragma unroll
            for (int nf = 0; nf < 5; nf++)
#pragma unroll
                for (int r = 0; r < 4; r++) acc[mt][nf][r] = 0.f;
        for (int k0 = 0; k0 < KPAD; k0 += 32) {
            f16x8 bf[5];
#pragma unroll
            for (int nf = 0; nf < 5; nf++)
                bf[nf] = *(const f16x8*)(bp + (size_t)nf * 16 * KPAD + k0);
#pragma unroll
            for (int mt = 0; mt < 4; mt++) {
                int arow = b * 256 + wbase + mt * 16 + (lane & 15);
                f16x8 af = *(const f16x8*)(x + (size_t)arow * KPAD + koff + k0);
#pragma unroll
                for (int nf = 0; nf < 5; nf++)
                    acc[mt][nf] = __builtin_amdgcn_mfma_f32_16x16x32_f16(af, bf[nf], acc[mt][nf], 0, 0, 0);
            }
        }
        // C/D: col=lane&15, row=(lane>>4)*4+reg [m89]. Permute cols + bias.
#pragma unroll
        for (int mt = 0; mt < 4; mt++)
#pragma unroll
            for (int nf = 0; nf < 5; nf++) {
                int g = nf * 16 + col;
                int pcol = (g % 40) * 2 + (g / 40);
#pragma unroll
                for (int r = 0; r < 4; r++) {
                    int word = wbase + mt * 16 + (lane >> 4) * 4 + r;
                    gb[word * G4 + pcol] = (_Float16)(acc[mt][nf][r] + bias_v[nf]);
                }
            }
        __syncthreads();   // single barrier; gemm waves exit
        return;
    }

    // ---- wave 0: recurrence constants ----
    const float* whh = dir ? whh_b : whh_f;
    int j = lane & 31; if (j > 19) j = 19;
    bool low = lane < 32;
    float mm = low ? 1.f : 2.f;
    float aa = low ? 0.f : -1.f;
    int coff = low ? (40 + 2 * j) : (2 * j);   // (f,o) | (i,g) pair, f16x2
    float w0[HH], w1[HH];
    {
        int r0 = low ? (20 + j) : j;
        int r1 = low ? (60 + j) : (40 + j);
#pragma unroll
        for (int k = 0; k < HH; k++) {
            w0[k] = LOG2E * whh[r0 * HH + k];
            w1[k] = LOG2E * whh[r1 * HH + k];
        }
    }
    __syncthreads();       // gates ready

    __builtin_amdgcn_s_setprio(1);
    const float TCM = -2.f * LOG2E;
    float h = 0.f, c = 0.f;
    int w = dir ? (WW - 1) : 0;
    int stepd = dir ? -1 : 1;

    union { unsigned int u; _Float16 hx[2]; } cu;
    cu.u = *(const unsigned int*)(gb + w * G4 + coff);
    float2 pre = make_float2((float)cu.hx[0], (float)cu.hx[1]);

    for (int sl = 0; sl < WW; ++sl) {
        int wn = w + stepd;
        int wnc = wn < 0 ? 0 : (wn > 255 ? 255 : wn);
        union { unsigned int u; _Float16 hx[2]; } nu;
        nu.u = *(const unsigned int*)(gb + wnc * G4 + coff);   // prefetch
        float a0a = pre.x, a0b = 0.f, a1a = pre.y, a1b = 0.f;
#pragma unroll
        for (int k = 0; k < 10; k++) {
            float hk  = __uint_as_float(__builtin_amdgcn_readlane(__float_as_uint(h), k));
            float hk2 = __uint_as_float(__builtin_amdgcn_readlane(__float_as_uint(h), k + 10));
            a0a = fmaf(hk,  w0[k],      a0a);
            a1a = fmaf(hk,  w1[k],      a1a);
            a0b = fmaf(hk2, w0[k + 10], a0b);
            a1b = fmaf(hk2, w1[k + 10], a1b);
        }
        float a0 = a0a + a0b, a1 = a1a + a1b;
        float u0 = 1.f / (1.f + exp2f(-a0));           // sig(f) | sig(i)
        float uu = 1.f / (1.f + exp2f(-mm * a1));
        float u1 = fmaf(uu, mm, aa);                   // sig(o) | tanh(g)
        float p  = u0 * u1;
        float ps = xchg32(p);                          // low gets sig(i)*tanh(g)
        c = fmaf(u0, c, ps);
        float tc = fmaf(2.f, 1.f / (1.f + exp2f(TCM * c)), -1.f);  // tanh(c)
        h = u1 * tc;
        if (lane < HH)
            out[((size_t)b * WW + w) * (2 * HH) + dir * HH + lane] = h;
        pre = make_float2((float)nu.hx[0], (float)nu.hx[1]);
        w = wn;
    }
    __builtin_amdgcn_s_setprio(0);
}

extern "C" void kernel_launch(void* const* d_in, const int* in_sizes, int n_in,
                              void* d_out, int out_size, void* d_ws, size_t ws_size,
                              hipStream_t stream) {
    const float* hiddens   = (const float*)d_in[0];
    const int*   bert2toks = (const int*)d_in[1];
    const int*   cap_inds  = (const int*)d_in[2];
    const float* cap_table = (const float*)d_in[3];
    const float* w_ih_f    = (const float*)d_in[4];
    const float* w_hh_f    = (const float*)d_in[5];
    const float* b_f       = (const float*)d_in[6];
    const float* w_ih_b    = (const float*)d_in[7];
    const float* w_hh_b    = (const float*)d_in[8];
    const float* b_b       = (const float*)d_in[9];
    float* out = (float*)d_out;

    _Float16* wpad = (_Float16*)((char*)d_ws + WP_OFF);
    int2*     seg  = (int2*)((char*)d_ws + SEG_OFF);
    _Float16* x    = (_Float16*)((char*)d_ws + X_OFF);

    k_prep<<<NOUT + BB, 256, 0, stream>>>(w_ih_f, w_ih_b, bert2toks, wpad, seg);
    k_mean<<<(BB * WW * 50) / 256, 256, 0, stream>>>(hiddens, seg, cap_inds, cap_table, x);
    k_lstm<<<128, 320, 0, stream>>>(x, wpad, b_f, b_b, w_hh_f, w_hh_b, out);
}

// Round 19
// 135.765 us; speedup vs baseline: 9.2592x; 1.1508x over previous
//
#include <hip/hip_runtime.h>
#include <math.h>

#define BB 64
#define T_SUB 512
#define WW 256
#define DD 768
#define HH 20
#define CAP_DIM 10
#define IN_DIM 778
#define KPAD 800
#define G4 80     // 4*H
#define NOUT 160
#define LOG2E 1.44269504f

typedef _Float16 f16x8 __attribute__((ext_vector_type(8)));
typedef float f32x4 __attribute__((ext_vector_type(4)));
typedef unsigned int uint2v __attribute__((ext_vector_type(2)));

// ws layout (bytes):
//   wpad : [160][800] f16   @ 0          (256,000 B)  -- PRE-SCALED by log2e
//   seg  : int2[16384]      @ 256,000    (131,072 B)
//   x    : [16384][800] f16 @ 387,072    (26,214,400 B)
#define WP_OFF   ((size_t)0)
#define SEG_OFF  ((size_t)256000)
#define X_OFF    ((size_t)387072)

// ---------------- K0: pad+scale weights (0..159) + segment search (160..223)
__global__ __launch_bounds__(256) void k_prep(
    const float* __restrict__ wf, const float* __restrict__ wb,
    const int* __restrict__ b2t,
    _Float16* __restrict__ wp, int2* __restrict__ seg)
{
    int blk = blockIdx.x;
    if (blk < NOUT) {
        int j = blk;
        const float* src = (j < G4) ? (wf + (size_t)j * IN_DIM)
                                    : (wb + (size_t)(j - G4) * IN_DIM);
        for (int k = threadIdx.x; k < KPAD; k += 256)
            wp[(size_t)j * KPAD + k] = (k < IN_DIM) ? (_Float16)(LOG2E * src[k])
                                                    : (_Float16)0.f;
    } else {
        int b = blk - NOUT, w = threadIdx.x;
        const int* row = b2t + (size_t)b * T_SUB;
        int lo = 0, hi = T_SUB;
        while (lo < hi) { int m = (lo + hi) >> 1; if (row[m] < w) lo = m + 1; else hi = m; }
        int lo2 = lo, hi2 = T_SUB;
        while (lo2 < hi2) { int m = (lo2 + hi2) >> 1; if (row[m] < w + 1) lo2 = m + 1; else hi2 = m; }
        seg[(size_t)b * WW + w] = make_int2(lo, lo2 - lo);
    }
}

// ---------------- K1: streaming mean -> fp16 x (R17-proven, unchanged) ------
__global__ __launch_bounds__(256) void k_mean(
    const float* __restrict__ hiddens, const int2* __restrict__ seg,
    const int* __restrict__ cap_inds, const float* __restrict__ cap_table,
    _Float16* __restrict__ x)
{
    int idx = blockIdx.x * 256 + threadIdx.x;   // 16384*50 total
    int d2 = idx % 50;
    int bw = idx / 50;
    int b = bw >> 8;
    int2 sg = seg[bw];
    int lo = sg.x, cnt = sg.y;
    const size_t LSTR = (size_t)BB * (T_SUB + 1) * DD;
    const float* rowp = hiddens + ((size_t)b * (T_SUB + 1) + lo + 1) * DD;
    float inv = 1.0f / (3.0f * (float)(cnt > 0 ? cnt : 1));
    bool bmean = (d2 + 50) < 96;
    f16x8 ra, rb;

    if (cnt == 2 && bmean) {
        const float* pa  = rowp + d2 * 8;
        const float* pb_ = rowp + (d2 + 50) * 8;
        float4 A0 = *(const float4*)(pa);                float4 A1 = *(const float4*)(pa + 4);
        float4 A2 = *(const float4*)(pa + DD);           float4 A3 = *(const float4*)(pa + DD + 4);
        float4 A4 = *(const float4*)(pa + LSTR);         float4 A5 = *(const float4*)(pa + LSTR + 4);
        float4 A6 = *(const float4*)(pa + LSTR + DD);    float4 A7 = *(const float4*)(pa + LSTR + DD + 4);
        float4 A8 = *(const float4*)(pa + 2*LSTR);       float4 A9 = *(const float4*)(pa + 2*LSTR + 4);
        float4 Aa = *(const float4*)(pa + 2*LSTR + DD);  float4 Ab = *(const float4*)(pa + 2*LSTR + DD + 4);
        float4 B0 = *(const float4*)(pb_);               float4 B1 = *(const float4*)(pb_ + 4);
        float4 B2 = *(const float4*)(pb_ + DD);          float4 B3 = *(const float4*)(pb_ + DD + 4);
        float4 B4 = *(const float4*)(pb_ + LSTR);        float4 B5 = *(const float4*)(pb_ + LSTR + 4);
        float4 B6 = *(const float4*)(pb_ + LSTR + DD);   float4 B7 = *(const float4*)(pb_ + LSTR + DD + 4);
        float4 B8 = *(const float4*)(pb_ + 2*LSTR);      float4 B9 = *(const float4*)(pb_ + 2*LSTR + 4);
        float4 Ba = *(const float4*)(pb_ + 2*LSTR + DD); float4 Bb = *(const float4*)(pb_ + 2*LSTR + DD + 4);
        ra[0] = (_Float16)((A0.x+A2.x+A4.x+A6.x+A8.x+Aa.x) * inv);
        ra[1] = (_Float16)((A0.y+A2.y+A4.y+A6.y+A8.y+Aa.y) * inv);
        ra[2] = (_Float16)((A0.z+A2.z+A4.z+A6.z+A8.z+Aa.z) * inv);
        ra[3] = (_Float16)((A0.w+A2.w+A4.w+A6.w+A8.w+Aa.w) * inv);
        ra[4] = (_Float16)((A1.x+A3.x+A5.x+A7.x+A9.x+Ab.x) * inv);
        ra[5] = (_Float16)((A1.y+A3.y+A5.y+A7.y+A9.y+Ab.y) * inv);
        ra[6] = (_Float16)((A1.z+A3.z+A5.z+A7.z+A9.z+Ab.z) * inv);
        ra[7] = (_Float16)((A1.w+A3.w+A5.w+A7.w+A9.w+Ab.w) * inv);
        rb[0] = (_Float16)((B0.x+B2.x+B4.x+B6.x+B8.x+Ba.x) * inv);
        rb[1] = (_Float16)((B0.y+B2.y+B4.y+B6.y+B8.y+Ba.y) * inv);
        rb[2] = (_Float16)((B0.z+B2.z+B4.z+B6.z+B8.z+Ba.z) * inv);
        rb[3] = (_Float16)((B0.w+B2.w+B4.w+B6.w+B8.w+Ba.w) * inv);
        rb[4] = (_Float16)((B1.x+B3.x+B5.x+B7.x+B9.x+Bb.x) * inv);
        rb[5] = (_Float16)((B1.y+B3.y+B5.y+B7.y+B9.y+Bb.y) * inv);
        rb[6] = (_Float16)((B1.z+B3.z+B5.z+B7.z+B9.z+Bb.z) * inv);
        rb[7] = (_Float16)((B1.w+B3.w+B5.w+B7.w+B9.w+Bb.w) * inv);
    } else {
        float a[8], bacc[8];
#pragma unroll
        for (int q = 0; q < 8; q++) { a[q] = 0.f; bacc[q] = 0.f; }
        for (int l = 0; l < 3; ++l)
            for (int ti = 0; ti < cnt; ++ti) {
                const float* p = rowp + l * LSTR + (size_t)ti * DD;
                float4 v0 = *(const float4*)(p + d2 * 8);
                float4 v1 = *(const float4*)(p + d2 * 8 + 4);
                a[0]+=v0.x; a[1]+=v0.y; a[2]+=v0.z; a[3]+=v0.w;
                a[4]+=v1.x; a[5]+=v1.y; a[6]+=v1.z; a[7]+=v1.w;
                if (bmean) {
                    float4 u0 = *(const float4*)(p + (d2 + 50) * 8);
                    float4 u1 = *(const float4*)(p + (d2 + 50) * 8 + 4);
                    bacc[0]+=u0.x; bacc[1]+=u0.y; bacc[2]+=u0.z; bacc[3]+=u0.w;
                    bacc[4]+=u1.x; bacc[5]+=u1.y; bacc[6]+=u1.z; bacc[7]+=u1.w;
                }
            }
#pragma unroll
        for (int q = 0; q < 8; q++) { ra[q] = (_Float16)(a[q] * inv); rb[q] = (_Float16)(bacc[q] * inv); }
    }
    if (!bmean) {
        int ci = cap_inds[bw];
#pragma unroll
        for (int q = 0; q < 8; q++) {
            int c = (d2 + 50 - 96) * 8 + q;
            rb[q] = (c < CAP_DIM) ? (_Float16)cap_table[ci * CAP_DIM + c] : (_Float16)0.f;
        }
    }
    *(f16x8*)(x + (size_t)bw * KPAD + d2 * 8) = ra;
    *(f16x8*)(x + (size_t)bw * KPAD + (d2 + 50) * 8) = rb;
}

// ---------------- K2: FUSED gemm+LSTM, all-chunks-upfront, solo chain -------
// R19 change: raw v_rcp_f32 / v_exp_f32 in the chain (precise-division
// sequences were ~100+ serial cycles/step on the critical path).
__device__ __forceinline__ float xchg32(float v) {
    unsigned int a = __float_as_uint(v);
    uint2v r = __builtin_amdgcn_permlane32_swap(a, a, false, false);
    return __uint_as_float(r[0] ^ r[1] ^ a);   // partner lane's value (lane ^ 32)
}
__device__ __forceinline__ float fex2(float v) { return __builtin_amdgcn_exp2f(v); }
__device__ __forceinline__ float frcp(float v) { return __builtin_amdgcn_rcpf(v); }

__global__ __launch_bounds__(320) void k_lstm(
    const _Float16* __restrict__ x, const _Float16* __restrict__ wp,
    const float* __restrict__ bias_f, const float* __restrict__ bias_b,
    const float* __restrict__ whh_f, const float* __restrict__ whh_b,
    float* __restrict__ out)
{
    __shared__ _Float16 gb[WW * G4];     // 40 KB: all 256 words' gates (f16)
    int dir  = blockIdx.x >> 6;
    int b    = blockIdx.x & 63;
    int t    = threadIdx.x;
    int wv   = t >> 6;
    int lane = t & 63;

    if (wv >= 1) {
        // ---- gemm: wave wv owns words [64*(wv-1), 64*wv), all 4 mtiles ----
        int col  = lane & 15;
        int koff = (lane >> 4) * 8;
        int wbase = (wv - 1) * 64;
        const _Float16* bp = wp + (size_t)(dir * G4 + col) * KPAD + koff;
        float bias_v[5];
#pragma unroll
        for (int nf = 0; nf < 5; nf++)
            bias_v[nf] = LOG2E * (dir ? bias_b : bias_f)[nf * 16 + col];
        f32x4 acc[4][5];
#pragma unroll
        for (int mt = 0; mt < 4; mt++)
#pragma unroll
            for (int nf = 0; nf < 5; nf++)
#pragma unroll
                for (int r = 0; r < 4; r++) acc[mt][nf][r] = 0.f;
        for (int k0 = 0; k0 < KPAD; k0 += 32) {
            f16x8 bf[5];
#pragma unroll
            for (int nf = 0; nf < 5; nf++)
                bf[nf] = *(const f16x8*)(bp + (size_t)nf * 16 * KPAD + k0);
#pragma unroll
            for (int mt = 0; mt < 4; mt++) {
                int arow = b * 256 + wbase + mt * 16 + (lane & 15);
                f16x8 af = *(const f16x8*)(x + (size_t)arow * KPAD + koff + k0);
#pragma unroll
                for (int nf = 0; nf < 5; nf++)
                    acc[mt][nf] = __builtin_amdgcn_mfma_f32_16x16x32_f16(af, bf[nf], acc[mt][nf], 0, 0, 0);
            }
        }
        // C/D: col=lane&15, row=(lane>>4)*4+reg [m89]. Permute cols + bias.
#pragma unroll
        for (int mt = 0; mt < 4; mt++)
#pragma unroll
            for (int nf = 0; nf < 5; nf++) {
                int g = nf * 16 + col;
                int pcol = (g % 40) * 2 + (g / 40);
#pragma unroll
                for (int r = 0; r < 4; r++) {
                    int word = wbase + mt * 16 + (lane >> 4) * 4 + r;
                    gb[word * G4 + pcol] = (_Float16)(acc[mt][nf][r] + bias_v[nf]);
                }
            }
        __syncthreads();   // single barrier; gemm waves exit
        return;
    }

    // ---- wave 0: recurrence constants ----
    const float* whh = dir ? whh_b : whh_f;
    int j = lane & 31; if (j > 19) j = 19;
    bool low = lane < 32;
    float mm = low ? 1.f : 2.f;
    float aa = low ? 0.f : -1.f;
    int coff = low ? (40 + 2 * j) : (2 * j);   // (f,o) | (i,g) pair, f16x2
    float w0[HH], w1[HH];
    {
        int r0 = low ? (20 + j) : j;
        int r1 = low ? (60 + j) : (40 + j);
#pragma unroll
        for (int k = 0; k < HH; k++) {
            w0[k] = LOG2E * whh[r0 * HH + k];
            w1[k] = LOG2E * whh[r1 * HH + k];
        }
    }
    __syncthreads();       // gates ready

    __builtin_amdgcn_s_setprio(1);
    const float TCM = -2.f * LOG2E;
    float h = 0.f, c = 0.f;
    int w = dir ? (WW - 1) : 0;
    int stepd = dir ? -1 : 1;

    union { unsigned int u; _Float16 hx[2]; } cu;
    cu.u = *(const unsigned int*)(gb + w * G4 + coff);
    float2 pre = make_float2((float)cu.hx[0], (float)cu.hx[1]);

    for (int sl = 0; sl < WW; ++sl) {
        int wn = w + stepd;
        int wnc = wn < 0 ? 0 : (wn > 255 ? 255 : wn);
        union { unsigned int u; _Float16 hx[2]; } nu;
        nu.u = *(const unsigned int*)(gb + wnc * G4 + coff);   // prefetch
        float a0a = pre.x, a0b = 0.f, a1a = pre.y, a1b = 0.f;
#pragma unroll
        for (int k = 0; k < 10; k++) {
            float hk  = __uint_as_float(__builtin_amdgcn_readlane(__float_as_uint(h), k));
            float hk2 = __uint_as_float(__builtin_amdgcn_readlane(__float_as_uint(h), k + 10));
            a0a = fmaf(hk,  w0[k],      a0a);
            a1a = fmaf(hk,  w1[k],      a1a);
            a0b = fmaf(hk2, w0[k + 10], a0b);
            a1b = fmaf(hk2, w1[k + 10], a1b);
        }
        float a0 = a0a + a0b, a1 = a1a + a1b;
        float u0 = frcp(1.f + fex2(-a0));              // sig(f) | sig(i)
        float uu = frcp(1.f + fex2(-mm * a1));
        float u1 = fmaf(uu, mm, aa);                   // sig(o) | tanh(g)
        float p  = u0 * u1;
        float ps = xchg32(p);                          // low gets sig(i)*tanh(g)
        c = fmaf(u0, c, ps);
        float tc = fmaf(2.f, frcp(1.f + fex2(TCM * c)), -1.f);  // tanh(c)
        h = u1 * tc;
        if (lane < HH)
            out[((size_t)b * WW + w) * (2 * HH) + dir * HH + lane] = h;
        pre = make_float2((float)nu.hx[0], (float)nu.hx[1]);
        w = wn;
    }
    __builtin_amdgcn_s_setprio(0);
}

extern "C" void kernel_launch(void* const* d_in, const int* in_sizes, int n_in,
                              void* d_out, int out_size, void* d_ws, size_t ws_size,
                              hipStream_t stream) {
    const float* hiddens   = (const float*)d_in[0];
    const int*   bert2toks = (const int*)d_in[1];
    const int*   cap_inds  = (const int*)d_in[2];
    const float* cap_table = (const float*)d_in[3];
    const float* w_ih_f    = (const float*)d_in[4];
    const float* w_hh_f    = (const float*)d_in[5];
    const float* b_f       = (const float*)d_in[6];
    const float* w_ih_b    = (const float*)d_in[7];
    const float* w_hh_b    = (const float*)d_in[8];
    const float* b_b       = (const float*)d_in[9];
    float* out = (float*)d_out;

    _Float16* wpad = (_Float16*)((char*)d_ws + WP_OFF);
    int2*     seg  = (int2*)((char*)d_ws + SEG_OFF);
    _Float16* x    = (_Float16*)((char*)d_ws + X_OFF);

    k_prep<<<NOUT + BB, 256, 0, stream>>>(w_ih_f, w_ih_b, bert2toks, wpad, seg);
    k_mean<<<(BB * WW * 50) / 256, 256, 0, stream>>>(hiddens, seg, cap_inds, cap_table, x);
    k_lstm<<<128, 320, 0, stream>>>(x, wpad, b_f, b_b, w_hh_f, w_hh_b, out);
}